// Round 11
// baseline (94.242 us; speedup 1.0000x reference)
//
#include <hip/hip_runtime.h>

// Chamfer distance: B=8, N=M=8192, D=3, fp32, via bf16 split-precision MFMA.
// R18 = R17 resubmitted (R10 bench was an infra failure: "container failed
//   twice" — no signal). Theory unchanged:
//   R15/R16 cross-check: L2 traffic halved (R16) -> flat; waves/SIMD
//   2.6 vs 4.4 -> flat; MfmaUtil pinned ~31% in both. Limiter is per-wave
//   issue structure: each 2-MFMA asm block is immediately followed by its
//   dependent 16-min3 group, so every wave waits out the MFMA result
//   latency (plus 10 nop cyc) before folding — and all waves stall in the
//   same pattern (206-410 cyc/MFMA/wave invariant).
//   Fix (ONE change): batch all 4 MFMA-pair blocks (dA..dD, 4 distinct
//   d-pairs = 128 regs) BEFORE any min3 group. group0's read of dA is now
//   ~200+ cyc after its producer (6 MFMAs + nops in between) -> latency
//   absorbed by MAI issue; groups 1-3 covered by preceding min3 work.
//   sched_barrier(0x34) after each block stops min3 hoisting into the nop
//   shadow; s_nop 7/3 kept per block (R12/R14-proven-correct producer).
//   Registers: d 128 + best 64 + cA/cB 32 + afrag 16 + addr ~6 = ~246
//   <= 256 @ launch_bounds(256,2). Spill tell: WRITE_SIZE in MBs -> revert.
//   Geometry/epilogue/prep: R16-identical (512 blocks, PPW=4, ping-pong).

#define B_DIM 8
#define N_DIM 8192
#define MT    (N_DIM / 32)      // 256 m-tiles per (dir,b)
#define BLOCK 256
#define PPW   4                 // n-tiles per wave

typedef short  bf16x8 __attribute__((ext_vector_type(8)));
typedef float  f32x16 __attribute__((ext_vector_type(16)));

__device__ __forceinline__ unsigned short bf16_rne(float f) {
    unsigned int u = __float_as_uint(f);
    u += 0x7fffu + ((u >> 16) & 1u);
    return (unsigned short)(u >> 16);
}
__device__ __forceinline__ float bf16f(unsigned short h) {
    return __uint_as_float(((unsigned int)h) << 16);
}

// Pack B-fragments for both directions. Layout: 16-byte frags indexed
// [dirb][mtile][half][m32] so a wave's 64 lanes read 1024 contiguous bytes.
__global__ __launch_bounds__(256) void chamfer_prep(
    const float* __restrict__ pred, const float* __restrict__ gt,
    unsigned short* __restrict__ bpack, float* __restrict__ out)
{
    const int i   = blockIdx.x * 256 + threadIdx.x;  // 0 .. 2*B*N-1
    if (i == 0) out[0] = 0.0f;
    const int dir = i >> 16;
    const int bm  = i & 0xFFFF;                      // b*N + m
    const float* dst = dir ? pred : gt;
    const float x = dst[3*bm+0], y = dst[3*bm+1], z = dst[3*bm+2];
    const unsigned short hx = bf16_rne(x), hy = bf16_rne(y), hz = bf16_rne(z);
    const unsigned short lx = bf16_rne(x - bf16f(hx));
    const unsigned short ly = bf16_rne(y - bf16f(hy));
    const unsigned short lz = bf16_rne(z - bf16f(hz));
    const float gn = x*x + y*y + z*z;
    const unsigned short gnh = bf16_rne(gn), gnl = bf16_rne(gn - bf16f(gnh));
    const unsigned short one = 0x3F80;

    const int b  = bm >> 13, m = bm & (N_DIM - 1);
    const int mt = m >> 5,   c = m & 31;
    const int dirb = (dir << 3) | b;
    unsigned short* p0 = bpack + ((size_t)(dirb * MT + mt) * 64 + c) * 8;
    unsigned short* p1 = p0 + 32 * 8;
    // half0 = k0..7 : gh(xyz) gl(xyz) gh(x,y) ; half1 = k8..15 : gh(z) 1 1 gnh gnl 0 0 0
    bf16x8 h0 = {(short)hx,(short)hy,(short)hz,(short)lx,(short)ly,(short)lz,(short)hx,(short)hy};
    bf16x8 h1 = {(short)hz,(short)one,(short)one,(short)gnh,(short)gnl,0,0,0};
    *(bf16x8*)p0 = h0;
    *(bf16x8*)p1 = h1;
}

__global__ __launch_bounds__(BLOCK, 2) void chamfer_partial(
    const float* __restrict__ pred, const float* __restrict__ gt,
    const bf16x8* __restrict__ bpack, float* __restrict__ out)
{
    __shared__ float cbuf[PPW * 16 * 128];  // 32 KB combine buffer (epilogue only)
    __shared__ float wsum[2];
    const int dirb = blockIdx.x;            // low grid bits -> XCD = dirb%8
    const int dir  = dirb >> 3, b = dirb & 7;
    const int w    = threadIdx.x >> 6, lane = threadIdx.x & 63;
    const int halfk = lane >> 5,  col = lane & 31;
    const int nsub = w & 1;                 // which n-tile quad
    const int mh   = w >> 1;                // m-half: 0 -> tiles 0..127, 1 -> 128..255

    const float* src  = dir ? gt : pred;
    const float* srcb = src + (size_t)b * N_DIM * 3;

    // A fragments for this wave's PPW n-tiles (row = col, k-half = halfk).
    bf16x8 afrag[PPW];
    #pragma unroll
    for (int p = 0; p < PPW; ++p) {
        const int ntile = blockIdx.y * 8 + nsub * PPW + p;
        const int n = ntile * 32 + col;
        const float x = srcb[3*n+0], y = srcb[3*n+1], z = srcb[3*n+2];
        const float ax = -2.f*x, ay = -2.f*y, az = -2.f*z;
        const unsigned short ahx = bf16_rne(ax), ahy = bf16_rne(ay), ahz = bf16_rne(az);
        const unsigned short alx = bf16_rne(ax - bf16f(ahx));
        const unsigned short aly = bf16_rne(ay - bf16f(ahy));
        const unsigned short alz = bf16_rne(az - bf16f(ahz));
        const float pn = x*x + y*y + z*z;
        const unsigned short pnh = bf16_rne(pn), pnl = bf16_rne(pn - bf16f(pnh));
        const unsigned short one = 0x3F80;
        bf16x8 a0 = {(short)ahx,(short)ahy,(short)ahz,(short)ahx,(short)ahy,(short)ahz,(short)alx,(short)aly};
        bf16x8 a1 = {(short)alz,(short)pnh,(short)pnl,(short)one,(short)one,0,0,0};
        afrag[p] = (halfk == 0) ? a0 : a1;
    }

    float best[PPW][16];
    #pragma unroll
    for (int p = 0; p < PPW; ++p)
        #pragma unroll
        for (int r = 0; r < 16; ++r) best[p][r] = 1e30f;

    // This wave's B-fragment stream: 128 m-tiles, 1 KB (wave) per tile,
    // coalesced dwordx4 per lane, L2-resident.
    const bf16x8* bw = bpack + (size_t)dirb * (MT * 64) + (size_t)(mh * 128) * 64 + lane;

    // One asm MFMA-pair block (R12/R14-proven producer: C = inline 0,
    // s_nop 7+3 in-asm; "=&v" forces arch VGPRs).
#define MBLK(dx_, dy_, af_, c0_, c1_) \
        asm volatile( \
            "v_mfma_f32_32x32x16_bf16 %0, %2, %3, 0\n\t" \
            "v_mfma_f32_32x32x16_bf16 %1, %2, %4, 0\n\t" \
            "s_nop 7\n\t" \
            "s_nop 3" \
            : "=&v"(dx_), "=&v"(dy_) \
            : "v"(af_), "v"(c0_), "v"(c1_)); \
        __builtin_amdgcn_sched_barrier(0x34);   // VALU may not cross up

#define MINGRP(bp_, dx_, dy_) \
        _Pragma("unroll") \
        for (int r = 0; r < 16; ++r) \
            asm("v_min3_f32 %0, %0, %1, %2" \
                : "+v"(best[bp_][r]) : "v"((dx_)[r]), "v"((dy_)[r]));

    // Batched FOLD: issue all 8 MFMAs (4 pair-blocks, 4 distinct d-pairs)
    // BEFORE any min3 group -> first consumer is ~200+ cyc downstream of
    // its producer; MFMA latency absorbed by MAI issue, not wave stall.
#define FOLD8(c0_, c1_) { \
        f32x16 dA0, dA1, dB0, dB1, dC0, dC1, dD0, dD1; \
        MBLK(dA0, dA1, afrag[0], c0_, c1_) \
        MBLK(dB0, dB1, afrag[1], c0_, c1_) \
        MBLK(dC0, dC1, afrag[2], c0_, c1_) \
        MBLK(dD0, dD1, afrag[3], c0_, c1_) \
        MINGRP(0, dA0, dA1) \
        MINGRP(1, dB0, dB1) \
        MINGRP(2, dC0, dC1) \
        MINGRP(3, dD0, dD1) \
    }

    // Copy-free x2 ping-pong: 64 tile-pair phases P0..P63. Each pair
    // reloads into ITS OWN registers right after the FOLD that kills it
    // (WAR orders load after consume; consumed one full phase later).
    bf16x8 cA0 = bw[0],   cA1 = bw[64];    // P0
    bf16x8 cB0 = bw[128], cB1 = bw[192];   // P1
    bw += 256;
    for (int t = 0; t < 31; ++t) {
        FOLD8(cA0, cA1);                   // fold P{2t}
        cA0 = bw[0];   cA1 = bw[64];       // load P{2t+2}
        FOLD8(cB0, cB1);                   // fold P{2t+1}
        cB0 = bw[128]; cB1 = bw[192];      // load P{2t+3}
        bw += 256;
    }
    FOLD8(cA0, cA1);                       // P62
    FOLD8(cB0, cB1);                       // P63

    // Combine the two m-halves: waves 2,3 export best[] through LDS,
    // waves 0,1 min-combine. Lanes contiguous -> conflict-free.
    if (mh == 1) {
        #pragma unroll
        for (int p = 0; p < PPW; ++p)
            #pragma unroll
            for (int r = 0; r < 16; ++r)
                cbuf[(p * 16 + r) * 128 + nsub * 64 + lane] = best[p][r];
    }
    __syncthreads();
    if (mh == 0) {
        float bsum = 0.f;
        #pragma unroll
        for (int p = 0; p < PPW; ++p) {
            float s = 0.f;
            #pragma unroll
            for (int r = 0; r < 16; ++r) {
                float v = fminf(best[p][r], cbuf[(p * 16 + r) * 128 + nsub * 64 + lane]);
                v = fminf(v, __shfl_xor(v, 1,  64));
                v = fminf(v, __shfl_xor(v, 2,  64));
                v = fminf(v, __shfl_xor(v, 4,  64));
                v = fminf(v, __shfl_xor(v, 8,  64));
                v = fminf(v, __shfl_xor(v, 16, 64));
                s += v;                       // 16 final row-mins of this k-half
            }
            bsum += s + __shfl_xor(s, 32, 64);  // add other k-half's 16 rows
        }
        if (lane == 0) wsum[nsub] = bsum;
    }
    __syncthreads();
    if (threadIdx.x == 0) {
        const float scale = 100.0f * 0.5f / ((float)B_DIM * (float)N_DIM);
        atomicAdd(out, (wsum[0] + wsum[1]) * scale);
    }
}

extern "C" void kernel_launch(void* const* d_in, const int* in_sizes, int n_in,
                              void* d_out, int out_size, void* d_ws, size_t ws_size,
                              hipStream_t stream) {
    const float* pred = (const float*)d_in[0];
    const float* gt   = (const float*)d_in[1];
    float* out = (float*)d_out;
    unsigned short* bpack = (unsigned short*)d_ws;   // 4 MiB

    chamfer_prep<<<(2 * B_DIM * N_DIM) / 256, 256, 0, stream>>>(pred, gt, bpack, out);

    // dirb x n-chunks(256 pts) = 16 x 32 = 512 blocks, 2/CU, 4 indep waves
    dim3 grid(16, N_DIM / 256);
    chamfer_partial<<<grid, BLOCK, 0, stream>>>(pred, gt, (const bf16x8*)bpack, out);
}

// Round 12
// 92.767 us; speedup vs baseline: 1.0159x; 1.0159x over previous
//
#include <hip/hip_runtime.h>

// Chamfer distance: B=8, N=M=8192, D=3, fp32, via bf16 split-precision MFMA.
// R19: R18 null (batched MFMAs = R16's immediate-consume, 43.3 vs 44.2us)
//   kills the MFMA-latency theory. Surviving suspect: bpack is written by
//   chamfer_prep on OTHER XCDs; L2 flushes at the kernel boundary, so the
//   partial kernel's B-stream is served by L3 (~500+cy loaded latency).
//   Load->use distance in every 43-52us variant is ONE phase (~400-450cy
//   of issue) -> each wave eats the ~300-400cy shortfall at the vmcnt
//   before every FOLD. Measured per-phase wave time 812cy vs ~420 issue
//   demand matches this in R15/R16/R18.
//   Fix (ONE change): prefetch depth 3 — four ping-pong pairs cA..cD,
//   each reloaded right after the FOLD that kills it (WAR-ordered, no
//   copies) and consumed THREE phases later (~1200+cy >> L3 latency).
//   vmcnt(6) before each FOLD then waits on 3-phase-old loads -> ~0 stall.
//   FOLD = R16's per-p form (R18 proved batching equivalent; per-p keeps
//   d-live at 32 regs). Peak regs ~184 < 256 @ launch_bounds(256,2).
//   Geometry/epilogue/prep: R16-identical (512 blocks, PPW=4).

#define B_DIM 8
#define N_DIM 8192
#define MT    (N_DIM / 32)      // 256 m-tiles per (dir,b)
#define BLOCK 256
#define PPW   4                 // n-tiles per wave

typedef short  bf16x8 __attribute__((ext_vector_type(8)));
typedef float  f32x16 __attribute__((ext_vector_type(16)));

__device__ __forceinline__ unsigned short bf16_rne(float f) {
    unsigned int u = __float_as_uint(f);
    u += 0x7fffu + ((u >> 16) & 1u);
    return (unsigned short)(u >> 16);
}
__device__ __forceinline__ float bf16f(unsigned short h) {
    return __uint_as_float(((unsigned int)h) << 16);
}

// Pack B-fragments for both directions. Layout: 16-byte frags indexed
// [dirb][mtile][half][m32] so a wave's 64 lanes read 1024 contiguous bytes.
__global__ __launch_bounds__(256) void chamfer_prep(
    const float* __restrict__ pred, const float* __restrict__ gt,
    unsigned short* __restrict__ bpack, float* __restrict__ out)
{
    const int i   = blockIdx.x * 256 + threadIdx.x;  // 0 .. 2*B*N-1
    if (i == 0) out[0] = 0.0f;
    const int dir = i >> 16;
    const int bm  = i & 0xFFFF;                      // b*N + m
    const float* dst = dir ? pred : gt;
    const float x = dst[3*bm+0], y = dst[3*bm+1], z = dst[3*bm+2];
    const unsigned short hx = bf16_rne(x), hy = bf16_rne(y), hz = bf16_rne(z);
    const unsigned short lx = bf16_rne(x - bf16f(hx));
    const unsigned short ly = bf16_rne(y - bf16f(hy));
    const unsigned short lz = bf16_rne(z - bf16f(hz));
    const float gn = x*x + y*y + z*z;
    const unsigned short gnh = bf16_rne(gn), gnl = bf16_rne(gn - bf16f(gnh));
    const unsigned short one = 0x3F80;

    const int b  = bm >> 13, m = bm & (N_DIM - 1);
    const int mt = m >> 5,   c = m & 31;
    const int dirb = (dir << 3) | b;
    unsigned short* p0 = bpack + ((size_t)(dirb * MT + mt) * 64 + c) * 8;
    unsigned short* p1 = p0 + 32 * 8;
    // half0 = k0..7 : gh(xyz) gl(xyz) gh(x,y) ; half1 = k8..15 : gh(z) 1 1 gnh gnl 0 0 0
    bf16x8 h0 = {(short)hx,(short)hy,(short)hz,(short)lx,(short)ly,(short)lz,(short)hx,(short)hy};
    bf16x8 h1 = {(short)hz,(short)one,(short)one,(short)gnh,(short)gnl,0,0,0};
    *(bf16x8*)p0 = h0;
    *(bf16x8*)p1 = h1;
}

__global__ __launch_bounds__(BLOCK, 2) void chamfer_partial(
    const float* __restrict__ pred, const float* __restrict__ gt,
    const bf16x8* __restrict__ bpack, float* __restrict__ out)
{
    __shared__ float cbuf[PPW * 16 * 128];  // 32 KB combine buffer (epilogue only)
    __shared__ float wsum[2];
    const int dirb = blockIdx.x;            // low grid bits -> XCD = dirb%8
    const int dir  = dirb >> 3, b = dirb & 7;
    const int w    = threadIdx.x >> 6, lane = threadIdx.x & 63;
    const int halfk = lane >> 5,  col = lane & 31;
    const int nsub = w & 1;                 // which n-tile quad
    const int mh   = w >> 1;                // m-half: 0 -> tiles 0..127, 1 -> 128..255

    const float* src  = dir ? gt : pred;
    const float* srcb = src + (size_t)b * N_DIM * 3;

    // A fragments for this wave's PPW n-tiles (row = col, k-half = halfk).
    bf16x8 afrag[PPW];
    #pragma unroll
    for (int p = 0; p < PPW; ++p) {
        const int ntile = blockIdx.y * 8 + nsub * PPW + p;
        const int n = ntile * 32 + col;
        const float x = srcb[3*n+0], y = srcb[3*n+1], z = srcb[3*n+2];
        const float ax = -2.f*x, ay = -2.f*y, az = -2.f*z;
        const unsigned short ahx = bf16_rne(ax), ahy = bf16_rne(ay), ahz = bf16_rne(az);
        const unsigned short alx = bf16_rne(ax - bf16f(ahx));
        const unsigned short aly = bf16_rne(ay - bf16f(ahy));
        const unsigned short alz = bf16_rne(az - bf16f(ahz));
        const float pn = x*x + y*y + z*z;
        const unsigned short pnh = bf16_rne(pn), pnl = bf16_rne(pn - bf16f(pnh));
        const unsigned short one = 0x3F80;
        bf16x8 a0 = {(short)ahx,(short)ahy,(short)ahz,(short)ahx,(short)ahy,(short)ahz,(short)alx,(short)aly};
        bf16x8 a1 = {(short)alz,(short)pnh,(short)pnl,(short)one,(short)one,0,0,0};
        afrag[p] = (halfk == 0) ? a0 : a1;
    }

    float best[PPW][16];
    #pragma unroll
    for (int p = 0; p < PPW; ++p)
        #pragma unroll
        for (int r = 0; r < 16; ++r) best[p][r] = 1e30f;

    // This wave's B-fragment stream: 128 m-tiles, 1 KB (wave) per tile,
    // coalesced dwordx4 per lane.
    const bf16x8* bw = bpack + (size_t)dirb * (MT * 64) + (size_t)(mh * 128) * 64 + lane;

    // Per n-tile p: MFMA pair in asm (C = inline 0; s_nop 7+3 in-asm
    // covers the MFMA->VALU read hazard), then per-element asm v_min3 on
    // arch VGPRs. R14/R16-proven correct; R18 proved batching equivalent,
    // so keep per-p (d-live = 32 regs).
#define FOLD(c0_, c1_) { \
        _Pragma("unroll") \
        for (int p = 0; p < PPW; ++p) { \
            f32x16 d0, d1; \
            asm volatile( \
                "v_mfma_f32_32x32x16_bf16 %0, %2, %3, 0\n\t" \
                "v_mfma_f32_32x32x16_bf16 %1, %2, %4, 0\n\t" \
                "s_nop 7\n\t" \
                "s_nop 3" \
                : "=&v"(d0), "=&v"(d1) \
                : "v"(afrag[p]), "v"(c0_), "v"(c1_)); \
            __builtin_amdgcn_sched_barrier(0x34); \
            _Pragma("unroll") \
            for (int r = 0; r < 16; ++r) \
                asm("v_min3_f32 %0, %0, %1, %2" \
                    : "+v"(best[p][r]) : "v"(d0[r]), "v"(d1[r])); \
        } \
    }

    // Depth-3 copy-free ping-pong: 64 tile-pair phases P0..P63 across four
    // register pairs. Each pair reloads into ITS OWN registers right after
    // the FOLD that kills it (WAR orders load after consume) and is next
    // consumed THREE phases later (~1200+ cyc) -> covers L3 latency.
    bf16x8 cA0 = bw[0],   cA1 = bw[64];    // P0
    bf16x8 cB0 = bw[128], cB1 = bw[192];   // P1
    bf16x8 cC0 = bw[256], cC1 = bw[320];   // P2
    bf16x8 cD0 = bw[384], cD1 = bw[448];   // P3
    bw += 512;
    for (int t = 0; t < 15; ++t) {
        FOLD(cA0, cA1);  cA0 = bw[0];   cA1 = bw[64];    // load P{4t+4}
        FOLD(cB0, cB1);  cB0 = bw[128]; cB1 = bw[192];   // load P{4t+5}
        FOLD(cC0, cC1);  cC0 = bw[256]; cC1 = bw[320];   // load P{4t+6}
        FOLD(cD0, cD1);  cD0 = bw[384]; cD1 = bw[448];   // load P{4t+7}
        bw += 512;
    }
    FOLD(cA0, cA1);                        // P60
    FOLD(cB0, cB1);                        // P61
    FOLD(cC0, cC1);                        // P62
    FOLD(cD0, cD1);                        // P63

    // Combine the two m-halves: waves 2,3 export best[] through LDS,
    // waves 0,1 min-combine. Lanes contiguous -> conflict-free.
    if (mh == 1) {
        #pragma unroll
        for (int p = 0; p < PPW; ++p)
            #pragma unroll
            for (int r = 0; r < 16; ++r)
                cbuf[(p * 16 + r) * 128 + nsub * 64 + lane] = best[p][r];
    }
    __syncthreads();
    if (mh == 0) {
        float bsum = 0.f;
        #pragma unroll
        for (int p = 0; p < PPW; ++p) {
            float s = 0.f;
            #pragma unroll
            for (int r = 0; r < 16; ++r) {
                float v = fminf(best[p][r], cbuf[(p * 16 + r) * 128 + nsub * 64 + lane]);
                v = fminf(v, __shfl_xor(v, 1,  64));
                v = fminf(v, __shfl_xor(v, 2,  64));
                v = fminf(v, __shfl_xor(v, 4,  64));
                v = fminf(v, __shfl_xor(v, 8,  64));
                v = fminf(v, __shfl_xor(v, 16, 64));
                s += v;                       // 16 final row-mins of this k-half
            }
            bsum += s + __shfl_xor(s, 32, 64);  // add other k-half's 16 rows
        }
        if (lane == 0) wsum[nsub] = bsum;
    }
    __syncthreads();
    if (threadIdx.x == 0) {
        const float scale = 100.0f * 0.5f / ((float)B_DIM * (float)N_DIM);
        atomicAdd(out, (wsum[0] + wsum[1]) * scale);
    }
}

extern "C" void kernel_launch(void* const* d_in, const int* in_sizes, int n_in,
                              void* d_out, int out_size, void* d_ws, size_t ws_size,
                              hipStream_t stream) {
    const float* pred = (const float*)d_in[0];
    const float* gt   = (const float*)d_in[1];
    float* out = (float*)d_out;
    unsigned short* bpack = (unsigned short*)d_ws;   // 4 MiB

    chamfer_prep<<<(2 * B_DIM * N_DIM) / 256, 256, 0, stream>>>(pred, gt, bpack, out);

    // dirb x n-chunks(256 pts) = 16 x 32 = 512 blocks, 2/CU, 4 indep waves
    dim3 grid(16, N_DIM / 256);
    chamfer_partial<<<grid, BLOCK, 0, stream>>>(pred, gt, (const bf16x8*)bpack, out);
}